// Round 19
// baseline (148.389 us; speedup 1.0000x reference)
//
#include <hip/hip_runtime.h>

// Mamba-2 SSD chunked scan — fused persistent kernel (round 19).
// Base = r18 (1 barrier/chunk, triangular-mask skips, lgkm-only barriers,
// compiler-scheduled loads). Round-19:
//  (a) XOR swizzle EXTENDED to Cm/Bm/Mm/St16 (was only Bt/Xt). The 16-row
//      b128 fragment reads at row stride 144B=36 dwords give bank-quad
//      4*(fr+fg) mod 32 -> 8-way aliasing; measured residual 9.65e6 conflict
//      cycles = 590cy/phase = 12%. Swizzle keyed by row, bits 4-6 only
//      (8B/16B alignment preserved, offsets stay < 144B row).
//  (b) St32 f32 state master LDS -> per-lane f32x4 REGISTER (same lane owns
//      the same (p,n) quad every chunk; no cross-lane exchange). Removes one
//      b128 read + one b128 write per phase and 8.7KB LDS.
// Canaries: conflicts <3e6, WRITE_SIZE==131072 KB, VGPR 64-72, absmax<=1.

typedef __bf16 bf16x4 __attribute__((ext_vector_type(4)));
typedef __bf16 bf16x8 __attribute__((ext_vector_type(8)));
typedef float  f32x4  __attribute__((ext_vector_type(4)));

constexpr int LDT = 72;   // bf16 row stride (144 B)

__device__ __forceinline__ f32x4 mfma16(bf16x8 a, bf16x8 b, f32x4 c) {
    return __builtin_amdgcn_mfma_f32_16x16x32_bf16(a, b, c, 0, 0, 0);
}
// LDS-only barrier: does NOT drain vmcnt (global reg-prefetches stay in flight)
__device__ __forceinline__ void bar_lds() {
    asm volatile("s_waitcnt lgkmcnt(0)\n\ts_barrier" ::: "memory");
}
// XOR swizzle keyed by row (bits 4-6 of byte offset; alignment-preserving)
__device__ __forceinline__ int swz(int row, int byteoff) {
    return byteoff ^ (((row >> 2) & 7) << 4);
}

struct SMemF {
    __bf16 Cm[2][64][LDT];   // C row-major [l][n]        (swizzled)
    __bf16 Bm[2][64][LDT];   // B row-major [l][n]        (swizzled)
    __bf16 Bt[2][64][LDT];   // B^T [n][l]                (swizzled)
    __bf16 Mm[2][64][LDT];   // M' [i][j]                 (swizzled)
    __bf16 Xt[3][32][LDT];   // Xs^T [p][l]               (swizzled, TRIPLE)
    __bf16 St16[2][32][LDT]; // state bf16 operand copy   (swizzled, parity)
    float  sY[2][64][36];    // Y staging (parity)
    float  ds[4][64];        // e^{cs63-cs_l}   } quad-buffered (c%4)
    float  dout[4][64];      // e^{cs_i}
    float  dlast[4];         // e^{cs63}
    float  dinv[4];          // e^{-cs63}
};

__global__ void ssd_fused(const float* __restrict__ Xg, const float* __restrict__ Ig,
                          const float* __restrict__ Ag, const float* __restrict__ Bg,
                          const float* __restrict__ Cg, float* __restrict__ Yg)
{
    const int ph = blockIdx.x, hh = blockIdx.y, bb = blockIdx.z;
    const int tid = threadIdx.x;            // 0..511
    const int wid = tid >> 6, lane = tid & 63;
    const int fr = lane & 15, fg = lane >> 4;
    const int iw2 = (wid >> 1) * 16;        // i-strip / n-strip
    const int pt  = (wid & 1) * 16;         // p-tile
    const int jh  = (wid & 1) * 32;         // G j-half base

    // mask-structure flags (wave-uniform)
    const bool dG0 = (jh      > iw2 + 15);
    const bool dG1 = (jh + 16 > iw2 + 15);
    const bool skipMm = dG0 && dG1;
    const bool adFull = (iw2 >= 32);

    __shared__ __align__(16) SMemF sm;
    const size_t tbase = (size_t)bb * 4096;

    const int half = tid >> 8;              // 0: B rows (+transpose), 1: C rows
    const int u    = tid & 255;
    const int lt0  = (u >> 4) * 4;
    const int rr0  = u >> 4;
    const int cq0  = (u & 15) * 4;
    const int xl  = tid >> 3;               // X/Y row 0..63
    const int xp4 = (tid & 7) * 4;          // X/Y p quad
    const int sp  = tid >> 4;               // St16 init row 0..31
    const int sn4 = (tid & 15) * 4;

    float rb[4][4], rx[4];
    float aA = 0.0f;
    f32x4 stReg;                            // f32 state master (per-lane quad)

    auto scan_to = [&](float v, int tb) {
        #pragma unroll
        for (int o = 1; o < 64; o <<= 1) { float t = __shfl_up(v, o, 64); if (lane >= o) v += t; }
        const float last = __shfl(v, 63, 64);
        sm.ds[tb][lane]   = expf(last - v);
        sm.dout[tb][lane] = expf(v);
        if (lane == 63) { sm.dlast[tb] = expf(v); sm.dinv[tb] = expf(-v); }
    };

    // ---------------- prologue ----------------
    {   // initial state: St16[0] (cooperative) + stReg (owning-lane quad)
        const size_t iofs = (((size_t)bb*16 + hh)*64 + (ph*32 + sp))*(size_t)64 + sn4;
        const float4 v = *reinterpret_cast<const float4*>(&Ig[iofs]);
        *reinterpret_cast<bf16x4*>(
            reinterpret_cast<char*>(&sm.St16[0][sp][0]) + swz(sp, sn4*2)) =
            (bf16x4){(__bf16)v.x, (__bf16)v.y, (__bf16)v.z, (__bf16)v.w};
        const size_t sofs = (((size_t)bb*16 + hh)*64 + (ph*32 + pt + fr))*(size_t)64 + iw2 + fg*4;
        const float4 s = *reinterpret_cast<const float4*>(&Ig[sofs]);
        stReg[0] = s.x; stReg[1] = s.y; stReg[2] = s.z; stReg[3] = s.w;
    }
    // chunk-0 loads
    #pragma unroll
    for (int j = 0; j < 4; ++j) {
        const int row = (half == 0) ? (lt0 + j) : (rr0 + 16*j);
        const size_t go = ((tbase + row)*16 + hh)*(size_t)64 + cq0;
        *reinterpret_cast<float4*>(rb[j]) = (half == 0)
            ? *reinterpret_cast<const float4*>(&Bg[go])
            : *reinterpret_cast<const float4*>(&Cg[go]);
    }
    *reinterpret_cast<float4*>(rx) =
        *reinterpret_cast<const float4*>(&Xg[((tbase + xl)*16 + hh)*(size_t)64 + ph*32 + xp4]);
    if (wid < 2) {   // scans for chunks 0,1
        const float v = Ag[(tbase + wid*64 + lane)*16 + hh];
        scan_to(v, wid);
    }
    // stage chunk-0 C/B/Bt into parity-0 buffers (all swizzled)
    if (half == 0) {
        #pragma unroll
        for (int j = 0; j < 4; ++j)
            *reinterpret_cast<bf16x4*>(
                reinterpret_cast<char*>(&sm.Bm[0][lt0 + j][0]) + swz(lt0 + j, cq0*2)) =
                (bf16x4){(__bf16)rb[j][0], (__bf16)rb[j][1], (__bf16)rb[j][2], (__bf16)rb[j][3]};
        #pragma unroll
        for (int q = 0; q < 4; ++q)
            *reinterpret_cast<bf16x4*>(
                reinterpret_cast<char*>(&sm.Bt[0][cq0 + q][0]) + swz(cq0 + q, lt0*2)) =
                (bf16x4){(__bf16)rb[0][q], (__bf16)rb[1][q], (__bf16)rb[2][q], (__bf16)rb[3][q]};
    } else {
        #pragma unroll
        for (int j = 0; j < 4; ++j)
            *reinterpret_cast<bf16x4*>(
                reinterpret_cast<char*>(&sm.Cm[0][rr0 + 16*j][0]) + swz(rr0 + 16*j, cq0*2)) =
                (bf16x4){(__bf16)rb[j][0], (__bf16)rb[j][1], (__bf16)rb[j][2], (__bf16)rb[j][3]};
    }
    bar_lds();   // tables[0],[1] + St16 + chunk-0 stage visible
    {   // stage Xt[0] (needs ds[0])
        const float dsl = sm.ds[0][xl];
        #pragma unroll
        for (int q = 0; q < 4; ++q)
            *reinterpret_cast<__bf16*>(
                reinterpret_cast<char*>(&sm.Xt[0][xp4 + q][0]) + swz(xp4 + q, xl*2)) =
                (__bf16)(rx[q] * dsl);
    }
    // chunk-1 loads; wave0 preloads A(2)
    #pragma unroll
    for (int j = 0; j < 4; ++j) {
        const int row = (half == 0) ? (lt0 + j) : (rr0 + 16*j);
        const size_t go = ((tbase + 64 + row)*16 + hh)*(size_t)64 + cq0;
        *reinterpret_cast<float4*>(rb[j]) = (half == 0)
            ? *reinterpret_cast<const float4*>(&Bg[go])
            : *reinterpret_cast<const float4*>(&Cg[go]);
    }
    *reinterpret_cast<float4*>(rx) =
        *reinterpret_cast<const float4*>(&Xg[((tbase + 64 + xl)*16 + hh)*(size_t)64 + ph*32 + xp4]);
    if (wid == 0) aA = Ag[(tbase + 2*64 + lane)*16 + hh];
    bar_lds();   // Xt[0] visible

    f32x4 aoprev = {};
    int x0 = 0, x1 = 1, x2 = 2;   // Xt buffers: c%3, (c+1)%3, (c-1)%3

    // ---------------- chunk loop: ONE barrier per chunk ----------------
    for (int c = 0; c < 64; ++c) {
        const int ci = c & 1, nb = ci ^ 1;
        const int t0 = c & 3, t1 = (c+1) & 3, t2 = (c+2) & 3, t3 = (c+3) & 3;

        // ---- MFMA cluster: chunk c (g/ao/st), dead G tiles skipped ----
        f32x4 g0 = {}, g1 = {}, aoacc = {}, stacc = {};
        #pragma unroll
        for (int ks = 0; ks < 2; ++ks) {
            const int k0 = ks*32 + fg*8;
            const bf16x8 aC  = *reinterpret_cast<const bf16x8*>(
                reinterpret_cast<const char*>(&sm.Cm[ci][iw2 + fr][0]) + swz(iw2 + fr, k0*2));
            const bf16x8 bSt = *reinterpret_cast<const bf16x8*>(
                reinterpret_cast<const char*>(&sm.St16[ci][pt + fr][0]) + swz(pt + fr, k0*2));
            const bf16x8 aBt = *reinterpret_cast<const bf16x8*>(
                reinterpret_cast<const char*>(&sm.Bt[ci][iw2 + fr][0]) + swz(iw2 + fr, k0*2));
            const bf16x8 bXt = *reinterpret_cast<const bf16x8*>(
                reinterpret_cast<const char*>(&sm.Xt[x0][pt + fr][0]) + swz(pt + fr, k0*2));
            aoacc = mfma16(aC,  bSt, aoacc);
            stacc = mfma16(aBt, bXt, stacc);
            if (!dG0) {
                const bf16x8 bB0 = *reinterpret_cast<const bf16x8*>(
                    reinterpret_cast<const char*>(&sm.Bm[ci][jh + fr][0]) + swz(jh + fr, k0*2));
                g0 = mfma16(aC, bB0, g0);
            }
            if (!dG1) {
                const bf16x8 bB1 = *reinterpret_cast<const bf16x8*>(
                    reinterpret_cast<const char*>(&sm.Bm[ci][jh + 16 + fr][0]) + swz(jh + 16 + fr, k0*2));
                g1 = mfma16(aC, bB1, g1);
            }
        }
        // ---- ad(c-1) = M'(c-1) @ Xs(c-1), triangular K ----
        f32x4 ad = {};
        if (c > 0) {
            {
                const int k0 = fg*8;
                const bf16x8 aM = *reinterpret_cast<const bf16x8*>(
                    reinterpret_cast<const char*>(&sm.Mm[nb][iw2 + fr][0]) + swz(iw2 + fr, k0*2));
                const bf16x8 bX = *reinterpret_cast<const bf16x8*>(
                    reinterpret_cast<const char*>(&sm.Xt[x2][pt + fr][0]) + swz(pt + fr, k0*2));
                ad = mfma16(aM, bX, ad);
            }
            if (adFull) {
                const int k0 = 32 + fg*8;
                const bf16x8 aM = *reinterpret_cast<const bf16x8*>(
                    reinterpret_cast<const char*>(&sm.Mm[nb][iw2 + fr][0]) + swz(iw2 + fr, k0*2));
                const bf16x8 bX = *reinterpret_cast<const bf16x8*>(
                    reinterpret_cast<const char*>(&sm.Xt[x2][pt + fr][0]) + swz(pt + fr, k0*2));
                ad = mfma16(aM, bX, ad);
            }
        }
        // ---- scan(c+2) -> tables[t2] ----
        if (c <= 61 && wid == 0) scan_to(aA, t2);
        // ---- Y store(c-2) from sY[nb] ----
        if (c >= 2) {
            const float4 v = *reinterpret_cast<const float4*>(&sm.sY[nb][xl][xp4]);
            *reinterpret_cast<float4*>(
                &Yg[((tbase + (size_t)(c-2)*64 + xl)*16 + hh)*(size_t)64 + ph*32 + xp4]) = v;
        }
        // ---- stage(c+1) into parity-nb / Xt[x1] (swizzled) ----
        if (c < 63) {
            if (half == 0) {
                #pragma unroll
                for (int j = 0; j < 4; ++j)
                    *reinterpret_cast<bf16x4*>(
                        reinterpret_cast<char*>(&sm.Bm[nb][lt0 + j][0]) + swz(lt0 + j, cq0*2)) =
                        (bf16x4){(__bf16)rb[j][0], (__bf16)rb[j][1], (__bf16)rb[j][2], (__bf16)rb[j][3]};
                #pragma unroll
                for (int q = 0; q < 4; ++q)
                    *reinterpret_cast<bf16x4*>(
                        reinterpret_cast<char*>(&sm.Bt[nb][cq0 + q][0]) + swz(cq0 + q, lt0*2)) =
                        (bf16x4){(__bf16)rb[0][q], (__bf16)rb[1][q], (__bf16)rb[2][q], (__bf16)rb[3][q]};
            } else {
                #pragma unroll
                for (int j = 0; j < 4; ++j)
                    *reinterpret_cast<bf16x4*>(
                        reinterpret_cast<char*>(&sm.Cm[nb][rr0 + 16*j][0]) + swz(rr0 + 16*j, cq0*2)) =
                        (bf16x4){(__bf16)rb[j][0], (__bf16)rb[j][1], (__bf16)rb[j][2], (__bf16)rb[j][3]};
            }
            const float dsl = sm.ds[t1][xl];
            #pragma unroll
            for (int q = 0; q < 4; ++q)
                *reinterpret_cast<__bf16*>(
                    reinterpret_cast<char*>(&sm.Xt[x1][xp4 + q][0]) + swz(xp4 + q, xl*2)) =
                    (__bf16)(rx[q] * dsl);
        }
        // ---- prefetch chunk c+2 (compiler-scheduled; r17 proved pinning hurts) ----
        if (c < 62) {
            const size_t s2 = tbase + (size_t)(c + 2)*64;
            #pragma unroll
            for (int j = 0; j < 4; ++j) {
                const int row = (half == 0) ? (lt0 + j) : (rr0 + 16*j);
                const size_t go = ((s2 + row)*16 + hh)*(size_t)64 + cq0;
                *reinterpret_cast<float4*>(rb[j]) = (half == 0)
                    ? *reinterpret_cast<const float4*>(&Bg[go])
                    : *reinterpret_cast<const float4*>(&Cg[go]);
            }
            *reinterpret_cast<float4*>(rx) =
                *reinterpret_cast<const float4*>(&Xg[((s2 + xl)*16 + hh)*(size_t)64 + ph*32 + xp4]);
        }
        if (wid == 0 && c <= 60) aA = Ag[(tbase + (size_t)(c + 3)*64 + lane)*16 + hh];
        // ---- sY[ci] write = Y(c-1) ----
        if (c > 0) {
            #pragma unroll
            for (int r = 0; r < 4; ++r) {
                const int i = iw2 + fg*4 + r;
                sm.sY[ci][i][pt + fr] = ad[r] + sm.dout[t3][i] * aoprev[r];
            }
        }
        // ---- Mm[ci] write = mask(G)*dout[i]*e^{-cs63} (swizzled; skip if unread) ----
        if (!skipMm) {
            const float dinvv = sm.dinv[t0];
            #pragma unroll
            for (int jt = 0; jt < 2; ++jt) {
                const int j = jh + jt*16 + fr;
                const f32x4& gg = jt ? g1 : g0;
                #pragma unroll
                for (int r = 0; r < 4; ++r) {
                    const int i = iw2 + fg*4 + r;
                    const float val = (i >= j) ? gg[r] * sm.dout[t0][i] * dinvv : 0.0f;
                    *reinterpret_cast<__bf16*>(
                        reinterpret_cast<char*>(&sm.Mm[ci][i][0]) + swz(i, j*2)) = (__bf16)val;
                }
            }
        }
        // ---- St update: stReg (register) + St16[nb] (swizzled) ----
        if (c < 63) {
            const float dl = sm.dlast[t0];
            f32x4 nv;
            nv[0] = fmaf(dl, stReg[0], stacc[0]); nv[1] = fmaf(dl, stReg[1], stacc[1]);
            nv[2] = fmaf(dl, stReg[2], stacc[2]); nv[3] = fmaf(dl, stReg[3], stacc[3]);
            stReg = nv;
            *reinterpret_cast<bf16x4*>(
                reinterpret_cast<char*>(&sm.St16[nb][pt + fr][0]) + swz(pt + fr, (iw2 + fg*4)*2)) =
                (bf16x4){(__bf16)nv[0], (__bf16)nv[1], (__bf16)nv[2], (__bf16)nv[3]};
        }
        aoprev = aoacc;
        bar_lds();   // the ONE barrier
        const int xt = x0; x0 = x1; x1 = x2; x2 = xt;   // rotate Xt buffers
    }

    // ---------------- epilogue: ad(63), Y(62), Y(63) ----------------
    {
        f32x4 ad = {};
        {
            const int k0 = fg*8;
            const bf16x8 aM = *reinterpret_cast<const bf16x8*>(
                reinterpret_cast<const char*>(&sm.Mm[1][iw2 + fr][0]) + swz(iw2 + fr, k0*2));
            const bf16x8 bX = *reinterpret_cast<const bf16x8*>(
                reinterpret_cast<const char*>(&sm.Xt[x2][pt + fr][0]) + swz(pt + fr, k0*2));
            ad = mfma16(aM, bX, ad);
        }
        if (adFull) {
            const int k0 = 32 + fg*8;
            const bf16x8 aM = *reinterpret_cast<const bf16x8*>(
                reinterpret_cast<const char*>(&sm.Mm[1][iw2 + fr][0]) + swz(iw2 + fr, k0*2));
            const bf16x8 bX = *reinterpret_cast<const bf16x8*>(
                reinterpret_cast<const char*>(&sm.Xt[x2][pt + fr][0]) + swz(pt + fr, k0*2));
            ad = mfma16(aM, bX, ad);
        }
        #pragma unroll
        for (int r = 0; r < 4; ++r) {
            const int i = iw2 + fg*4 + r;
            sm.sY[0][i][pt + fr] = ad[r] + sm.dout[3][i] * aoprev[r];
        }
    }
    {   // Y(62) from sY[1]
        const float4 v = *reinterpret_cast<const float4*>(&sm.sY[1][xl][xp4]);
        *reinterpret_cast<float4*>(
            &Yg[((tbase + (size_t)62*64 + xl)*16 + hh)*(size_t)64 + ph*32 + xp4]) = v;
    }
    bar_lds();
    {   // Y(63) from sY[0]
        const float4 v = *reinterpret_cast<const float4*>(&sm.sY[0][xl][xp4]);
        *reinterpret_cast<float4*>(
            &Yg[((tbase + (size_t)63*64 + xl)*16 + hh)*(size_t)64 + ph*32 + xp4]) = v;
    }
}

extern "C" void kernel_launch(void* const* d_in, const int* in_sizes, int n_in,
                              void* d_out, int out_size, void* d_ws, size_t ws_size,
                              hipStream_t stream) {
    const float* X  = (const float*)d_in[0];
    const float* I  = (const float*)d_in[1];
    const float* A  = (const float*)d_in[2];
    const float* Bp = (const float*)d_in[3];
    const float* Cp = (const float*)d_in[4];
    float* Y = (float*)d_out;
    ssd_fused<<<dim3(2, 16, 8), 512, 0, stream>>>(X, I, A, Bp, Cp, Y);
}

// Round 20
// 134.105 us; speedup vs baseline: 1.1065x; 1.1065x over previous
//
#include <hip/hip_runtime.h>

// Mamba-2 SSD chunked scan — fused persistent kernel (FINAL = round 13, best
// measured: 131.5us). One barrier per chunk; all same-phase hazards removed by
// buffering: Cm/Bm/Bt/Mm/St16/sY double-buffered (parity), Xt TRIPLE-buffered,
// decay tables QUAD-buffered with scan TWO chunks ahead. lgkm-only barriers
// (vmcnt stays in flight); XOR swizzle on transposed Bt/Xt; loads left to
// compiler scheduling (r17 proved pinning is a loss; r14-16: private-array
// addressing/indexing => scratch; r18 skips and r19 swizzle-extension both
// regressed the bench). LDS ~124KB -> 1 block/CU by construction.

typedef __bf16 bf16x4 __attribute__((ext_vector_type(4)));
typedef __bf16 bf16x8 __attribute__((ext_vector_type(8)));
typedef float  f32x4  __attribute__((ext_vector_type(4)));

constexpr int LDT = 72;   // bf16 row stride (144 B)

__device__ __forceinline__ f32x4 mfma16(bf16x8 a, bf16x8 b, f32x4 c) {
    return __builtin_amdgcn_mfma_f32_16x16x32_bf16(a, b, c, 0, 0, 0);
}
// LDS-only barrier: does NOT drain vmcnt (global reg-prefetches stay in flight)
__device__ __forceinline__ void bar_lds() {
    asm volatile("s_waitcnt lgkmcnt(0)\n\ts_barrier" ::: "memory");
}
// XOR swizzle for transposed buffers (16B granularity, rows grouped by 4)
__device__ __forceinline__ int swz(int row, int byteoff) {
    return byteoff ^ (((row >> 2) & 7) << 4);
}

struct SMemF {
    __bf16 Cm[2][64][LDT];   // C row-major [l][n]
    __bf16 Bm[2][64][LDT];   // B row-major [l][n]
    __bf16 Bt[2][64][LDT];   // B^T [n][l] (swizzled)
    __bf16 Mm[2][64][LDT];   // M' [i][j]
    __bf16 Xt[3][32][LDT];   // Xs^T [p][l] (swizzled, TRIPLE)
    __bf16 St16[2][32][LDT]; // state bf16 operand copy (parity)
    float  St32[32][68];     // state f32 master (per-lane exclusive)
    float  sY[2][64][36];    // Y staging (parity)
    float  ds[4][64];        // e^{cs63-cs_l}   } quad-buffered (c%4):
    float  dout[4][64];      // e^{cs_i}        } scan(c+2) writes (c+2)%4 while
    float  douti[4][64];     // e^{cs_i-cs63}   } c,c+1,c-1 still being read
    float  dlast[4];         // e^{cs63}
};

__global__ void ssd_fused(const float* __restrict__ Xg, const float* __restrict__ Ig,
                          const float* __restrict__ Ag, const float* __restrict__ Bg,
                          const float* __restrict__ Cg, float* __restrict__ Yg)
{
    const int ph = blockIdx.x, hh = blockIdx.y, bb = blockIdx.z;
    const int tid = threadIdx.x;            // 0..511
    const int wid = tid >> 6, lane = tid & 63;
    const int fr = lane & 15, fg = lane >> 4;
    const int iw2 = (wid >> 1) * 16;        // i-strip / n-strip
    const int pt  = (wid & 1) * 16;         // p-tile
    const int jh  = (wid & 1) * 32;         // G j-half base

    __shared__ __align__(16) SMemF sm;
    const size_t tbase = (size_t)bb * 4096;

    const int half = tid >> 8;              // 0: B rows (+transpose), 1: C rows
    const int u    = tid & 255;
    const int lt0  = (u >> 4) * 4;
    const int rr0  = u >> 4;
    const int cq0  = (u & 15) * 4;
    const int xl  = tid >> 3;               // X/Y row 0..63
    const int xp4 = (tid & 7) * 4;          // X/Y p quad
    const int sp  = tid >> 4;               // St row 0..31
    const int sn4 = (tid & 15) * 4;

    float rb[4][4], rx[4];
    float aA = 0.0f;

    auto scan_to = [&](float v, int tb) {
        #pragma unroll
        for (int o = 1; o < 64; o <<= 1) { float t = __shfl_up(v, o, 64); if (lane >= o) v += t; }
        const float last = __shfl(v, 63, 64);
        sm.ds[tb][lane]    = expf(last - v);
        sm.dout[tb][lane]  = expf(v);
        sm.douti[tb][lane] = expf(v - last);
        if (lane == 63) sm.dlast[tb] = expf(v);
    };

    // ---------------- prologue ----------------
    {   // initial state -> St32 + St16[0]
        const size_t iofs = (((size_t)bb*16 + hh)*64 + (ph*32 + sp))*(size_t)64 + sn4;
        const float4 v = *reinterpret_cast<const float4*>(&Ig[iofs]);
        sm.St32[sp][sn4+0] = v.x; sm.St32[sp][sn4+1] = v.y;
        sm.St32[sp][sn4+2] = v.z; sm.St32[sp][sn4+3] = v.w;
        *reinterpret_cast<bf16x4*>(&sm.St16[0][sp][sn4]) =
            (bf16x4){(__bf16)v.x, (__bf16)v.y, (__bf16)v.z, (__bf16)v.w};
    }
    // chunk-0 loads
    #pragma unroll
    for (int j = 0; j < 4; ++j) {
        const int row = (half == 0) ? (lt0 + j) : (rr0 + 16*j);
        const size_t go = ((tbase + row)*16 + hh)*(size_t)64 + cq0;
        *reinterpret_cast<float4*>(rb[j]) = (half == 0)
            ? *reinterpret_cast<const float4*>(&Bg[go])
            : *reinterpret_cast<const float4*>(&Cg[go]);
    }
    *reinterpret_cast<float4*>(rx) =
        *reinterpret_cast<const float4*>(&Xg[((tbase + xl)*16 + hh)*(size_t)64 + ph*32 + xp4]);
    // scans for chunks 0,1 (waves 0,1 in parallel)
    if (wid < 2) {
        const float v = Ag[(tbase + wid*64 + lane)*16 + hh];
        scan_to(v, wid);
    }
    // stage chunk-0 C/B/Bt into parity-0 buffers
    if (half == 0) {
        #pragma unroll
        for (int j = 0; j < 4; ++j)
            *reinterpret_cast<bf16x4*>(&sm.Bm[0][lt0 + j][cq0]) =
                (bf16x4){(__bf16)rb[j][0], (__bf16)rb[j][1], (__bf16)rb[j][2], (__bf16)rb[j][3]};
        #pragma unroll
        for (int q = 0; q < 4; ++q)
            *reinterpret_cast<bf16x4*>(
                reinterpret_cast<char*>(&sm.Bt[0][cq0 + q][0]) + swz(cq0 + q, lt0*2)) =
                (bf16x4){(__bf16)rb[0][q], (__bf16)rb[1][q], (__bf16)rb[2][q], (__bf16)rb[3][q]};
    } else {
        #pragma unroll
        for (int j = 0; j < 4; ++j)
            *reinterpret_cast<bf16x4*>(&sm.Cm[0][rr0 + 16*j][cq0]) =
                (bf16x4){(__bf16)rb[j][0], (__bf16)rb[j][1], (__bf16)rb[j][2], (__bf16)rb[j][3]};
    }
    bar_lds();   // tables[0],[1] + St + chunk-0 stage visible
    {   // stage Xt[0] (needs ds[0])
        const float dsl = sm.ds[0][xl];
        #pragma unroll
        for (int q = 0; q < 4; ++q)
            *reinterpret_cast<__bf16*>(
                reinterpret_cast<char*>(&sm.Xt[0][xp4 + q][0]) + swz(xp4 + q, xl*2)) =
                (__bf16)(rx[q] * dsl);
    }
    // chunk-1 loads (rb consumed above); wave0 preloads A(2)
    #pragma unroll
    for (int j = 0; j < 4; ++j) {
        const int row = (half == 0) ? (lt0 + j) : (rr0 + 16*j);
        const size_t go = ((tbase + 64 + row)*16 + hh)*(size_t)64 + cq0;
        *reinterpret_cast<float4*>(rb[j]) = (half == 0)
            ? *reinterpret_cast<const float4*>(&Bg[go])
            : *reinterpret_cast<const float4*>(&Cg[go]);
    }
    *reinterpret_cast<float4*>(rx) =
        *reinterpret_cast<const float4*>(&Xg[((tbase + 64 + xl)*16 + hh)*(size_t)64 + ph*32 + xp4]);
    if (wid == 0) aA = Ag[(tbase + 2*64 + lane)*16 + hh];
    bar_lds();   // Xt[0] visible

    f32x4 aoprev = {};
    int x0 = 0, x1 = 1, x2 = 2;   // Xt buffers: c%3, (c+1)%3, (c-1)%3

    // ---------------- chunk loop: ONE barrier per chunk ----------------
    for (int c = 0; c < 64; ++c) {
        const int ci = c & 1, nb = ci ^ 1;
        const int t0 = c & 3, t1 = (c+1) & 3, t2 = (c+2) & 3, t3 = (c+3) & 3;

        // ---- MFMA cluster: chunk c (g/ao/st) ----
        f32x4 g0 = {}, g1 = {}, aoacc = {}, stacc = {};
        #pragma unroll
        for (int ks = 0; ks < 2; ++ks) {
            const int k0 = ks*32 + fg*8;
            const bf16x8 aC  = *reinterpret_cast<const bf16x8*>(&sm.Cm[ci][iw2 + fr][k0]);
            const bf16x8 bB0 = *reinterpret_cast<const bf16x8*>(&sm.Bm[ci][jh      + fr][k0]);
            const bf16x8 bB1 = *reinterpret_cast<const bf16x8*>(&sm.Bm[ci][jh + 16 + fr][k0]);
            const bf16x8 bSt = *reinterpret_cast<const bf16x8*>(&sm.St16[ci][pt + fr][k0]);
            const bf16x8 aBt = *reinterpret_cast<const bf16x8*>(
                reinterpret_cast<const char*>(&sm.Bt[ci][iw2 + fr][0]) + swz(iw2 + fr, k0*2));
            const bf16x8 bXt = *reinterpret_cast<const bf16x8*>(
                reinterpret_cast<const char*>(&sm.Xt[x0][pt + fr][0]) + swz(pt + fr, k0*2));
            g0    = mfma16(aC,  bB0, g0);
            g1    = mfma16(aC,  bB1, g1);
            aoacc = mfma16(aC,  bSt, aoacc);
            stacc = mfma16(aBt, bXt, stacc);
        }
        // ---- ad(c-1) = M'(c-1) @ Xs(c-1) ----
        f32x4 ad = {};
        if (c > 0) {
            #pragma unroll
            for (int ks = 0; ks < 2; ++ks) {
                const int k0 = ks*32 + fg*8;
                const bf16x8 aM = *reinterpret_cast<const bf16x8*>(&sm.Mm[nb][iw2 + fr][k0]);
                const bf16x8 bX = *reinterpret_cast<const bf16x8*>(
                    reinterpret_cast<const char*>(&sm.Xt[x2][pt + fr][0]) + swz(pt + fr, k0*2));
                ad = mfma16(aM, bX, ad);
            }
        }
        // ---- scan(c+2) -> tables[t2] ----
        if (c <= 61 && wid == 0) scan_to(aA, t2);
        // ---- Y store(c-2) from sY[nb] ----
        if (c >= 2) {
            const float4 v = *reinterpret_cast<const float4*>(&sm.sY[nb][xl][xp4]);
            *reinterpret_cast<float4*>(
                &Yg[((tbase + (size_t)(c-2)*64 + xl)*16 + hh)*(size_t)64 + ph*32 + xp4]) = v;
        }
        // ---- stage(c+1) into parity-nb / Xt[x1] ----
        if (c < 63) {
            if (half == 0) {
                #pragma unroll
                for (int j = 0; j < 4; ++j)
                    *reinterpret_cast<bf16x4*>(&sm.Bm[nb][lt0 + j][cq0]) =
                        (bf16x4){(__bf16)rb[j][0], (__bf16)rb[j][1], (__bf16)rb[j][2], (__bf16)rb[j][3]};
                #pragma unroll
                for (int q = 0; q < 4; ++q)
                    *reinterpret_cast<bf16x4*>(
                        reinterpret_cast<char*>(&sm.Bt[nb][cq0 + q][0]) + swz(cq0 + q, lt0*2)) =
                        (bf16x4){(__bf16)rb[0][q], (__bf16)rb[1][q], (__bf16)rb[2][q], (__bf16)rb[3][q]};
            } else {
                #pragma unroll
                for (int j = 0; j < 4; ++j)
                    *reinterpret_cast<bf16x4*>(&sm.Cm[nb][rr0 + 16*j][cq0]) =
                        (bf16x4){(__bf16)rb[j][0], (__bf16)rb[j][1], (__bf16)rb[j][2], (__bf16)rb[j][3]};
            }
            const float dsl = sm.ds[t1][xl];
            #pragma unroll
            for (int q = 0; q < 4; ++q)
                *reinterpret_cast<__bf16*>(
                    reinterpret_cast<char*>(&sm.Xt[x1][xp4 + q][0]) + swz(xp4 + q, xl*2)) =
                    (__bf16)(rx[q] * dsl);
        }
        // ---- prefetch chunk c+2 (rb consumed by stage above) ----
        if (c < 62) {
            const size_t s2 = tbase + (size_t)(c + 2)*64;
            #pragma unroll
            for (int j = 0; j < 4; ++j) {
                const int row = (half == 0) ? (lt0 + j) : (rr0 + 16*j);
                const size_t go = ((s2 + row)*16 + hh)*(size_t)64 + cq0;
                *reinterpret_cast<float4*>(rb[j]) = (half == 0)
                    ? *reinterpret_cast<const float4*>(&Bg[go])
                    : *reinterpret_cast<const float4*>(&Cg[go]);
            }
            *reinterpret_cast<float4*>(rx) =
                *reinterpret_cast<const float4*>(&Xg[((s2 + xl)*16 + hh)*(size_t)64 + ph*32 + xp4]);
        }
        if (wid == 0 && c <= 60) aA = Ag[(tbase + (size_t)(c + 3)*64 + lane)*16 + hh];
        // ---- sY[ci] write = Y(c-1) ----
        if (c > 0) {
            #pragma unroll
            for (int r = 0; r < 4; ++r) {
                const int i = iw2 + fg*4 + r;
                sm.sY[ci][i][pt + fr] = ad[r] + sm.dout[t3][i] * aoprev[r];
            }
        }
        // ---- Mm[ci] write = mask(G)*e^{cs_i-cs63} ----
        #pragma unroll
        for (int jt = 0; jt < 2; ++jt) {
            const int j = jh + jt*16 + fr;
            const f32x4& gg = jt ? g1 : g0;
            #pragma unroll
            for (int r = 0; r < 4; ++r) {
                const int i = iw2 + fg*4 + r;
                const float val = (i >= j) ? gg[r] * sm.douti[t0][i] : 0.0f;
                sm.Mm[ci][i][j] = (__bf16)val;
            }
        }
        // ---- St update -> St32 + St16[nb] ----
        if (c < 63) {
            const float dl = sm.dlast[t0];
            const int p = pt + fr, n0 = iw2 + fg*4;
            const float4 ov = *reinterpret_cast<const float4*>(&sm.St32[p][n0]);
            float4 nv;
            nv.x = fmaf(dl, ov.x, stacc[0]); nv.y = fmaf(dl, ov.y, stacc[1]);
            nv.z = fmaf(dl, ov.z, stacc[2]); nv.w = fmaf(dl, ov.w, stacc[3]);
            *reinterpret_cast<float4*>(&sm.St32[p][n0]) = nv;
            *reinterpret_cast<bf16x4*>(&sm.St16[nb][p][n0]) =
                (bf16x4){(__bf16)nv.x, (__bf16)nv.y, (__bf16)nv.z, (__bf16)nv.w};
        }
        aoprev = aoacc;
        bar_lds();   // the ONE barrier
        const int xt = x0; x0 = x1; x1 = x2; x2 = xt;   // rotate Xt buffers
    }

    // ---------------- epilogue: ad(63), Y(62), Y(63) ----------------
    {
        f32x4 ad = {};
        #pragma unroll
        for (int ks = 0; ks < 2; ++ks) {
            const int k0 = ks*32 + fg*8;
            const bf16x8 aM = *reinterpret_cast<const bf16x8*>(&sm.Mm[1][iw2 + fr][k0]);
            const bf16x8 bX = *reinterpret_cast<const bf16x8*>(
                reinterpret_cast<const char*>(&sm.Xt[x2][pt + fr][0]) + swz(pt + fr, k0*2));
            ad = mfma16(aM, bX, ad);
        }
        #pragma unroll
        for (int r = 0; r < 4; ++r) {
            const int i = iw2 + fg*4 + r;
            sm.sY[0][i][pt + fr] = ad[r] + sm.dout[3][i] * aoprev[r];
        }
    }
    {   // Y(62) from sY[1] (written in phase 63; loop-end barrier synced)
        const float4 v = *reinterpret_cast<const float4*>(&sm.sY[1][xl][xp4]);
        *reinterpret_cast<float4*>(
            &Yg[((tbase + (size_t)62*64 + xl)*16 + hh)*(size_t)64 + ph*32 + xp4]) = v;
    }
    bar_lds();
    {   // Y(63) from sY[0]
        const float4 v = *reinterpret_cast<const float4*>(&sm.sY[0][xl][xp4]);
        *reinterpret_cast<float4*>(
            &Yg[((tbase + (size_t)63*64 + xl)*16 + hh)*(size_t)64 + ph*32 + xp4]) = v;
    }
}

extern "C" void kernel_launch(void* const* d_in, const int* in_sizes, int n_in,
                              void* d_out, int out_size, void* d_ws, size_t ws_size,
                              hipStream_t stream) {
    const float* X  = (const float*)d_in[0];
    const float* I  = (const float*)d_in[1];
    const float* A  = (const float*)d_in[2];
    const float* Bp = (const float*)d_in[3];
    const float* Cp = (const float*)d_in[4];
    float* Y = (float*)d_out;
    ssd_fused<<<dim3(2, 16, 8), 512, 0, stream>>>(X, I, A, Bp, Cp, Y);
}